// Round 1
// baseline (1092.983 us; speedup 1.0000x reference)
//
#include <hip/hip_runtime.h>

// ---------------------------------------------------------------------------
// GCN forward:  relu(x@W1+b1) -> gcnconv(Wc1) -> relu -> gcnconv(Wc2) -> relu
//               -> @W2 + b2
// gcnconv(h) = scatter_add(norm[e] * (h@W)[row[e]] -> col[e]) + dinv^2*(h@W) + b
// norm[e] = dinv[row]*ew*dinv[col],  deg[c] = 1 + sum(ew over col edges)
// ---------------------------------------------------------------------------

__global__ __launch_bounds__(256) void k_init_deg(float* __restrict__ deg, int n) {
    int i = blockIdx.x * 256 + threadIdx.x;
    if (i < n) deg[i] = 1.0f;   // self-loop weight
}

__global__ __launch_bounds__(256) void k_deg_accum(const int* __restrict__ col,
                                                   const float* __restrict__ ew,
                                                   float* __restrict__ deg, int ne) {
    int i = blockIdx.x * 256 + threadIdx.x;
    if (i < ne) atomicAdd(&deg[col[i]], ew[i]);
}

__global__ __launch_bounds__(256) void k_dinv(float* __restrict__ deg, int n) {
    int i = blockIdx.x * 256 + threadIdx.x;
    if (i < n) deg[i] = rsqrtf(deg[i]);   // deg >= 1 always (self-loop)
}

// ---------------------------------------------------------------------------
// GEMM1: h = relu(x @ W1 + b1);  x[N,256], W1[256,64].
// Block: 256 threads, 64 rows x 64 cols tile, K in 4 chunks of 64.
// Microtile 4x4 per thread.
// ---------------------------------------------------------------------------
__global__ __launch_bounds__(256) void k_gemm1(const float* __restrict__ x,
                                               const float* __restrict__ W,
                                               const float* __restrict__ bias,
                                               float* __restrict__ h, int n) {
    __shared__ float xs[64 * 68];   // 64 rows, stride 68 (16B-aligned, bank-spread)
    __shared__ float ws[64 * 64];
    const int tid = threadIdx.x;
    const int row0 = blockIdx.x * 64;
    const int tx = tid & 15, ty = tid >> 4;
    float acc[4][4] = {};

    for (int kb = 0; kb < 256; kb += 64) {
        __syncthreads();
        // stage W chunk (contiguous 4096 floats)
        {
            const float4* src = (const float4*)(W + kb * 64);
            float4* dst = (float4*)ws;
#pragma unroll
            for (int i = 0; i < 4; ++i) dst[tid + i * 256] = src[tid + i * 256];
        }
        // stage x tile: 64 rows x 64 k
#pragma unroll
        for (int i = 0; i < 4; ++i) {
            int f = tid + i * 256;        // float4 index in tile
            int r = f >> 4;               // row 0..63
            int c = (f & 15) * 4;         // col 0..60
            int row = row0 + r;
            float4 v = make_float4(0.f, 0.f, 0.f, 0.f);
            if (row < n) v = *(const float4*)(x + (size_t)row * 256 + kb + c);
            *(float4*)(xs + r * 68 + c) = v;
        }
        __syncthreads();
#pragma unroll
        for (int kk = 0; kk < 64; kk += 4) {
            float4 a[4], b[4];
#pragma unroll
            for (int j = 0; j < 4; ++j)
                a[j] = *(const float4*)(xs + (ty * 4 + j) * 68 + kk);
#pragma unroll
            for (int q = 0; q < 4; ++q)
                b[q] = *(const float4*)(ws + (kk + q) * 64 + tx * 4);
#pragma unroll
            for (int j = 0; j < 4; ++j) {
                float aj[4] = {a[j].x, a[j].y, a[j].z, a[j].w};
#pragma unroll
                for (int q = 0; q < 4; ++q) {
                    acc[j][0] = fmaf(aj[q], b[q].x, acc[j][0]);
                    acc[j][1] = fmaf(aj[q], b[q].y, acc[j][1]);
                    acc[j][2] = fmaf(aj[q], b[q].z, acc[j][2]);
                    acc[j][3] = fmaf(aj[q], b[q].w, acc[j][3]);
                }
            }
        }
    }
    float4 bb = *(const float4*)(bias + tx * 4);
#pragma unroll
    for (int j = 0; j < 4; ++j) {
        int row = row0 + ty * 4 + j;
        if (row < n) {
            float4 o;
            o.x = fmaxf(acc[j][0] + bb.x, 0.f);
            o.y = fmaxf(acc[j][1] + bb.y, 0.f);
            o.z = fmaxf(acc[j][2] + bb.z, 0.f);
            o.w = fmaxf(acc[j][3] + bb.w, 0.f);
            *(float4*)(h + (size_t)row * 64 + tx * 4) = o;
        }
    }
}

// ---------------------------------------------------------------------------
// Conv dense part: t = (relu?)(hin) @ W;  agg = bias + dinv^2 * t  (self-loop
// term + bias folded into agg init). Writes both t and agg.
// ---------------------------------------------------------------------------
template <bool RELU_IN>
__global__ __launch_bounds__(256) void k_conv(const float* __restrict__ hin,
                                              const float* __restrict__ W,
                                              const float* __restrict__ bias,
                                              const float* __restrict__ dinv,
                                              float* __restrict__ t,
                                              float* __restrict__ agg, int n) {
    __shared__ float xs[64 * 68];
    __shared__ float ws[64 * 64];
    const int tid = threadIdx.x;
    const int row0 = blockIdx.x * 64;
    const int tx = tid & 15, ty = tid >> 4;

    {
        const float4* src = (const float4*)W;
        float4* dst = (float4*)ws;
#pragma unroll
        for (int i = 0; i < 4; ++i) dst[tid + i * 256] = src[tid + i * 256];
    }
#pragma unroll
    for (int i = 0; i < 4; ++i) {
        int f = tid + i * 256;
        int r = f >> 4;
        int c = (f & 15) * 4;
        int row = row0 + r;
        float4 v = make_float4(0.f, 0.f, 0.f, 0.f);
        if (row < n) {
            v = *(const float4*)(hin + (size_t)row * 64 + c);
            if (RELU_IN) {
                v.x = fmaxf(v.x, 0.f); v.y = fmaxf(v.y, 0.f);
                v.z = fmaxf(v.z, 0.f); v.w = fmaxf(v.w, 0.f);
            }
        }
        *(float4*)(xs + r * 68 + c) = v;
    }
    __syncthreads();

    float acc[4][4] = {};
#pragma unroll
    for (int kk = 0; kk < 64; kk += 4) {
        float4 a[4], b[4];
#pragma unroll
        for (int j = 0; j < 4; ++j)
            a[j] = *(const float4*)(xs + (ty * 4 + j) * 68 + kk);
#pragma unroll
        for (int q = 0; q < 4; ++q)
            b[q] = *(const float4*)(ws + (kk + q) * 64 + tx * 4);
#pragma unroll
        for (int j = 0; j < 4; ++j) {
            float aj[4] = {a[j].x, a[j].y, a[j].z, a[j].w};
#pragma unroll
            for (int q = 0; q < 4; ++q) {
                acc[j][0] = fmaf(aj[q], b[q].x, acc[j][0]);
                acc[j][1] = fmaf(aj[q], b[q].y, acc[j][1]);
                acc[j][2] = fmaf(aj[q], b[q].z, acc[j][2]);
                acc[j][3] = fmaf(aj[q], b[q].w, acc[j][3]);
            }
        }
    }
    float4 bb = *(const float4*)(bias + tx * 4);
#pragma unroll
    for (int j = 0; j < 4; ++j) {
        int row = row0 + ty * 4 + j;
        if (row < n) {
            float dv = dinv[row];
            float s = dv * dv;
            float4 tv = make_float4(acc[j][0], acc[j][1], acc[j][2], acc[j][3]);
            *(float4*)(t + (size_t)row * 64 + tx * 4) = tv;
            float4 av = make_float4(bb.x + s * tv.x, bb.y + s * tv.y,
                                    bb.z + s * tv.z, bb.w + s * tv.w);
            *(float4*)(agg + (size_t)row * 64 + tx * 4) = av;
        }
    }
}

// ---------------------------------------------------------------------------
// Edge aggregation: one wave per edge, lane = feature.
// agg[col, f] += dinv[row]*ew*dinv[col] * t[row, f]
// ---------------------------------------------------------------------------
__global__ __launch_bounds__(256) void k_edge_agg(const int* __restrict__ row,
                                                  const int* __restrict__ col,
                                                  const float* __restrict__ ew,
                                                  const float* __restrict__ dinv,
                                                  const float* __restrict__ t,
                                                  float* __restrict__ agg, int ne) {
    const int lane = threadIdx.x & 63;
    const int e = blockIdx.x * 4 + (threadIdx.x >> 6);
    if (e >= ne) return;
    const int r = row[e];
    const int c = col[e];
    const float nrm = dinv[r] * ew[e] * dinv[c];
    const float v = nrm * t[(size_t)r * 64 + lane];
    atomicAdd(&agg[(size_t)c * 64 + lane], v);
}

// ---------------------------------------------------------------------------
// Final: out = relu(hin) @ W2 + b2;  W2[64,40]
// ---------------------------------------------------------------------------
__global__ __launch_bounds__(256) void k_final(const float* __restrict__ hin,
                                               const float* __restrict__ W,
                                               const float* __restrict__ bias,
                                               float* __restrict__ out, int n) {
    __shared__ float xs[64 * 68];
    __shared__ float ws[64 * 40];  // 2560 floats
    const int tid = threadIdx.x;
    const int row0 = blockIdx.x * 64;

    for (int i = tid; i < 640; i += 256)
        ((float4*)ws)[i] = ((const float4*)W)[i];
#pragma unroll
    for (int i = 0; i < 4; ++i) {
        int f = tid + i * 256;
        int r = f >> 4;
        int c = (f & 15) * 4;
        int row = row0 + r;
        float4 v = make_float4(0.f, 0.f, 0.f, 0.f);
        if (row < n) {
            v = *(const float4*)(hin + (size_t)row * 64 + c);
            v.x = fmaxf(v.x, 0.f); v.y = fmaxf(v.y, 0.f);
            v.z = fmaxf(v.z, 0.f); v.w = fmaxf(v.w, 0.f);
        }
        *(float4*)(xs + r * 68 + c) = v;
    }
    __syncthreads();

    const int tx = tid & 15, ty = tid >> 4;
    if (tx < 10) {  // 40 output cols = 10 groups of 4
        float acc[4][4] = {};
#pragma unroll
        for (int kk = 0; kk < 64; kk += 4) {
            float4 a[4], b[4];
#pragma unroll
            for (int j = 0; j < 4; ++j)
                a[j] = *(const float4*)(xs + (ty * 4 + j) * 68 + kk);
#pragma unroll
            for (int q = 0; q < 4; ++q)
                b[q] = *(const float4*)(ws + (kk + q) * 40 + tx * 4);
#pragma unroll
            for (int j = 0; j < 4; ++j) {
                float aj[4] = {a[j].x, a[j].y, a[j].z, a[j].w};
#pragma unroll
                for (int q = 0; q < 4; ++q) {
                    acc[j][0] = fmaf(aj[q], b[q].x, acc[j][0]);
                    acc[j][1] = fmaf(aj[q], b[q].y, acc[j][1]);
                    acc[j][2] = fmaf(aj[q], b[q].z, acc[j][2]);
                    acc[j][3] = fmaf(aj[q], b[q].w, acc[j][3]);
                }
            }
        }
        float4 bb = *(const float4*)(bias + tx * 4);
#pragma unroll
        for (int j = 0; j < 4; ++j) {
            int row = row0 + ty * 4 + j;
            if (row < n) {
                float4 o = make_float4(acc[j][0] + bb.x, acc[j][1] + bb.y,
                                       acc[j][2] + bb.z, acc[j][3] + bb.w);
                *(float4*)(out + (size_t)row * 40 + tx * 4) = o;
            }
        }
    }
}

extern "C" void kernel_launch(void* const* d_in, const int* in_sizes, int n_in,
                              void* d_out, int out_size, void* d_ws, size_t ws_size,
                              hipStream_t stream) {
    const float* x   = (const float*)d_in[0];
    const int*   ei  = (const int*)d_in[1];
    const float* ew  = (const float*)d_in[2];
    const float* W1  = (const float*)d_in[3];
    const float* b1  = (const float*)d_in[4];
    const float* Wc1 = (const float*)d_in[5];
    const float* bc1 = (const float*)d_in[6];
    const float* Wc2 = (const float*)d_in[7];
    const float* bc2 = (const float*)d_in[8];
    const float* W2  = (const float*)d_in[9];
    const float* b2  = (const float*)d_in[10];
    float* out = (float*)d_out;

    const int N = in_sizes[0] / 256;
    const int E = in_sizes[2];
    const int* row = ei;        // edge_index[0]
    const int* col = ei + E;    // edge_index[1]

    // workspace layout (floats): deg/dinv[N] | bufA[N*64] | bufB[N*64] | bufC[N*64]
    float* deg  = (float*)d_ws;
    float* bufA = deg + N;                     // h1, later t2
    float* bufB = bufA + (size_t)N * 64;       // t1, later agg2
    float* bufC = bufB + (size_t)N * 64;       // agg1

    const int gN = (N + 255) / 256;
    const int gE = (E + 255) / 256;
    const int gG = (N + 63) / 64;
    const int gA = (E + 3) / 4;

    k_init_deg<<<gN, 256, 0, stream>>>(deg, N);
    k_deg_accum<<<gE, 256, 0, stream>>>(col, ew, deg, E);
    k_dinv<<<gN, 256, 0, stream>>>(deg, N);

    // layer 1: h1 = relu(x@W1+b1)
    k_gemm1<<<gG, 256, 0, stream>>>(x, W1, b1, bufA, N);

    // conv1: t1 = h1@Wc1; agg1 = bc1 + dinv^2*t1; then edge scatter
    k_conv<false><<<gG, 256, 0, stream>>>(bufA, Wc1, bc1, deg, bufB, bufC, N);
    k_edge_agg<<<gA, 256, 0, stream>>>(row, col, ew, deg, bufB, bufC, E);

    // conv2: input relu(agg1); t2 -> bufA, agg2 -> bufB
    k_conv<true><<<gG, 256, 0, stream>>>(bufC, Wc2, bc2, deg, bufA, bufB, N);
    k_edge_agg<<<gA, 256, 0, stream>>>(row, col, ew, deg, bufA, bufB, E);

    // out = relu(agg2) @ W2 + b2
    k_final<<<gG, 256, 0, stream>>>(bufB, W2, b2, out, N);
}

// Round 2
// 696.484 us; speedup vs baseline: 1.5693x; 1.5693x over previous
//
#include <hip/hip_runtime.h>

// ---------------------------------------------------------------------------
// GCN forward:  relu(x@W1+b1) -> gcnconv(Wc1) -> relu -> gcnconv(Wc2) -> relu
//               -> @W2 + b2
//
// R2: atomic scatter replaced by CSR gather. Edges counting-sorted by col
// (destination) once per call; both convs aggregate with one wave per node,
// no global atomics. Record = {row:int, norm:float} (8 B).
// ---------------------------------------------------------------------------

__global__ __launch_bounds__(256) void k_init(float* __restrict__ deg,
                                              int* __restrict__ cnt, int n) {
    int i = blockIdx.x * 256 + threadIdx.x;
    if (i < n) { deg[i] = 1.0f; cnt[i] = 0; }   // self-loop weight; histogram zero
}

__global__ __launch_bounds__(256) void k_deg_accum(const int* __restrict__ col,
                                                   const float* __restrict__ ew,
                                                   float* __restrict__ deg,
                                                   int* __restrict__ cnt, int ne) {
    int i = blockIdx.x * 256 + threadIdx.x;
    if (i < ne) {
        int c = col[i];
        atomicAdd(&deg[c], ew[i]);
        atomicAdd(&cnt[c], 1);
    }
}

__global__ __launch_bounds__(256) void k_dinv(float* __restrict__ deg, int n) {
    int i = blockIdx.x * 256 + threadIdx.x;
    if (i < n) deg[i] = rsqrtf(deg[i]);   // deg >= 1 always (self-loop)
}

// --- two-level exclusive scan of cnt[n] -> ptr ----------------------------
__global__ __launch_bounds__(256) void k_scan1(const int* __restrict__ cnt,
                                               int* __restrict__ ptr,
                                               int* __restrict__ bsum, int n) {
    __shared__ int s[256];
    const int t = threadIdx.x;
    const int i = blockIdx.x * 256 + t;
    int v = (i < n) ? cnt[i] : 0;
    s[t] = v;
    __syncthreads();
#pragma unroll
    for (int off = 1; off < 256; off <<= 1) {
        int x = (t >= off) ? s[t - off] : 0;
        __syncthreads();
        s[t] += x;
        __syncthreads();
    }
    if (i < n) ptr[i] = s[t] - v;            // local exclusive
    if (t == 255) bsum[blockIdx.x] = s[255]; // block total
}

__global__ __launch_bounds__(512) void k_scan2(int* __restrict__ bsum, int nb) {
    __shared__ int s[512];
    const int t = threadIdx.x;
    int v = (t < nb) ? bsum[t] : 0;
    s[t] = v;
    __syncthreads();
#pragma unroll
    for (int off = 1; off < 512; off <<= 1) {
        int x = (t >= off) ? s[t - off] : 0;
        __syncthreads();
        s[t] += x;
        __syncthreads();
    }
    if (t < nb) bsum[t] = s[t] - v;          // exclusive block offsets
}

__global__ __launch_bounds__(256) void k_scan3(int* __restrict__ ptr,
                                               const int* __restrict__ bsum,
                                               int* __restrict__ cursor,
                                               int n, int etot) {
    int i = blockIdx.x * 256 + threadIdx.x;
    if (i < n) {
        int p = ptr[i] + bsum[i >> 8];
        ptr[i] = p;
        cursor[i] = p;
    }
    if (i == 0) ptr[n] = etot;
}

// --- scatter edges into CSR order, precomputing norm ----------------------
__global__ __launch_bounds__(256) void k_scatter(const int* __restrict__ row,
                                                 const int* __restrict__ col,
                                                 const float* __restrict__ ew,
                                                 const float* __restrict__ dinv,
                                                 int* __restrict__ cursor,
                                                 int2* __restrict__ recs, int ne) {
    int i = blockIdx.x * 256 + threadIdx.x;
    if (i < ne) {
        int r = row[i], c = col[i];
        float nrm = dinv[r] * ew[i] * dinv[c];
        int pos = atomicAdd(&cursor[c], 1);
        recs[pos] = make_int2(r, __float_as_int(nrm));
    }
}

// ---------------------------------------------------------------------------
// GEMM1: h = relu(x @ W1 + b1);  x[N,256], W1[256,64]. 64x64 tile, 4x4 micro.
// ---------------------------------------------------------------------------
__global__ __launch_bounds__(256) void k_gemm1(const float* __restrict__ x,
                                               const float* __restrict__ W,
                                               const float* __restrict__ bias,
                                               float* __restrict__ h, int n) {
    __shared__ float xs[64 * 68];
    __shared__ float ws[64 * 64];
    const int tid = threadIdx.x;
    const int row0 = blockIdx.x * 64;
    const int tx = tid & 15, ty = tid >> 4;
    float acc[4][4] = {};

    for (int kb = 0; kb < 256; kb += 64) {
        __syncthreads();
        {
            const float4* src = (const float4*)(W + kb * 64);
            float4* dst = (float4*)ws;
#pragma unroll
            for (int i = 0; i < 4; ++i) dst[tid + i * 256] = src[tid + i * 256];
        }
#pragma unroll
        for (int i = 0; i < 4; ++i) {
            int f = tid + i * 256;
            int r = f >> 4;
            int c = (f & 15) * 4;
            int row = row0 + r;
            float4 v = make_float4(0.f, 0.f, 0.f, 0.f);
            if (row < n) v = *(const float4*)(x + (size_t)row * 256 + kb + c);
            *(float4*)(xs + r * 68 + c) = v;
        }
        __syncthreads();
#pragma unroll
        for (int kk = 0; kk < 64; kk += 4) {
            float4 a[4], b[4];
#pragma unroll
            for (int j = 0; j < 4; ++j)
                a[j] = *(const float4*)(xs + (ty * 4 + j) * 68 + kk);
#pragma unroll
            for (int q = 0; q < 4; ++q)
                b[q] = *(const float4*)(ws + (kk + q) * 64 + tx * 4);
#pragma unroll
            for (int j = 0; j < 4; ++j) {
                float aj[4] = {a[j].x, a[j].y, a[j].z, a[j].w};
#pragma unroll
                for (int q = 0; q < 4; ++q) {
                    acc[j][0] = fmaf(aj[q], b[q].x, acc[j][0]);
                    acc[j][1] = fmaf(aj[q], b[q].y, acc[j][1]);
                    acc[j][2] = fmaf(aj[q], b[q].z, acc[j][2]);
                    acc[j][3] = fmaf(aj[q], b[q].w, acc[j][3]);
                }
            }
        }
    }
    float4 bb = *(const float4*)(bias + tx * 4);
#pragma unroll
    for (int j = 0; j < 4; ++j) {
        int row = row0 + ty * 4 + j;
        if (row < n) {
            float4 o;
            o.x = fmaxf(acc[j][0] + bb.x, 0.f);
            o.y = fmaxf(acc[j][1] + bb.y, 0.f);
            o.z = fmaxf(acc[j][2] + bb.z, 0.f);
            o.w = fmaxf(acc[j][3] + bb.w, 0.f);
            *(float4*)(h + (size_t)row * 64 + tx * 4) = o;
        }
    }
}

// ---------------------------------------------------------------------------
// Conv dense part: t = hin @ W (pure 64x64 GEMM; bias/self-loop live in k_agg)
// ---------------------------------------------------------------------------
__global__ __launch_bounds__(256) void k_conv(const float* __restrict__ hin,
                                              const float* __restrict__ W,
                                              float* __restrict__ t, int n) {
    __shared__ float xs[64 * 68];
    __shared__ float ws[64 * 64];
    const int tid = threadIdx.x;
    const int row0 = blockIdx.x * 64;
    const int tx = tid & 15, ty = tid >> 4;

    {
        const float4* src = (const float4*)W;
        float4* dst = (float4*)ws;
#pragma unroll
        for (int i = 0; i < 4; ++i) dst[tid + i * 256] = src[tid + i * 256];
    }
#pragma unroll
    for (int i = 0; i < 4; ++i) {
        int f = tid + i * 256;
        int r = f >> 4;
        int c = (f & 15) * 4;
        int row = row0 + r;
        float4 v = make_float4(0.f, 0.f, 0.f, 0.f);
        if (row < n) v = *(const float4*)(hin + (size_t)row * 64 + c);
        *(float4*)(xs + r * 68 + c) = v;
    }
    __syncthreads();

    float acc[4][4] = {};
#pragma unroll
    for (int kk = 0; kk < 64; kk += 4) {
        float4 a[4], b[4];
#pragma unroll
        for (int j = 0; j < 4; ++j)
            a[j] = *(const float4*)(xs + (ty * 4 + j) * 68 + kk);
#pragma unroll
        for (int q = 0; q < 4; ++q)
            b[q] = *(const float4*)(ws + (kk + q) * 64 + tx * 4);
#pragma unroll
        for (int j = 0; j < 4; ++j) {
            float aj[4] = {a[j].x, a[j].y, a[j].z, a[j].w};
#pragma unroll
            for (int q = 0; q < 4; ++q) {
                acc[j][0] = fmaf(aj[q], b[q].x, acc[j][0]);
                acc[j][1] = fmaf(aj[q], b[q].y, acc[j][1]);
                acc[j][2] = fmaf(aj[q], b[q].z, acc[j][2]);
                acc[j][3] = fmaf(aj[q], b[q].w, acc[j][3]);
            }
        }
    }
#pragma unroll
    for (int j = 0; j < 4; ++j) {
        int row = row0 + ty * 4 + j;
        if (row < n)
            *(float4*)(t + (size_t)row * 64 + tx * 4) =
                make_float4(acc[j][0], acc[j][1], acc[j][2], acc[j][3]);
    }
}

// ---------------------------------------------------------------------------
// CSR aggregation: one wave per node c.
//   agg[c] = relu( b + dinv[c]^2 * t[c] + sum_e norm_e * t[row_e] )
// Lane layout: grp = lane>>4 (edge slot 0..3), f4 = lane&15 (float4 of feature).
// 4 edges in flight per iteration, 16B/lane gathers; shfl-reduce across grps.
// ---------------------------------------------------------------------------
__global__ __launch_bounds__(256) void k_agg(const int* __restrict__ ptr,
                                             const int2* __restrict__ recs,
                                             const float* __restrict__ dinv,
                                             const float* __restrict__ bias,
                                             const float4* __restrict__ t4,
                                             float4* __restrict__ agg4, int n) {
    const int lane = threadIdx.x & 63;
    const int c = blockIdx.x * 4 + (threadIdx.x >> 6);
    if (c >= n) return;
    const int grp = lane >> 4;
    const int f4 = lane & 15;

    float4 acc = make_float4(0.f, 0.f, 0.f, 0.f);
    if (grp == 0) {
        float dv = dinv[c];
        float s = dv * dv;
        float4 tv = t4[(size_t)c * 16 + f4];
        float4 bb = ((const float4*)bias)[f4];
        acc.x = fmaf(s, tv.x, bb.x);
        acc.y = fmaf(s, tv.y, bb.y);
        acc.z = fmaf(s, tv.z, bb.z);
        acc.w = fmaf(s, tv.w, bb.w);
    }

    const int eEnd = ptr[c + 1];
    int e = ptr[c] + grp;
    int2 rec = (e < eEnd) ? recs[e] : make_int2(0, 0);
    while (e < eEnd) {
        int2 cur = rec;
        e += 4;
        if (e < eEnd) rec = recs[e];
        float w = __int_as_float(cur.y);
        float4 tv = t4[(size_t)cur.x * 16 + f4];
        acc.x = fmaf(w, tv.x, acc.x);
        acc.y = fmaf(w, tv.y, acc.y);
        acc.z = fmaf(w, tv.z, acc.z);
        acc.w = fmaf(w, tv.w, acc.w);
    }

    // reduce across the 4 groups (lanes differing in bits 4,5)
#pragma unroll
    for (int off = 16; off < 64; off <<= 1) {
        acc.x += __shfl_xor(acc.x, off, 64);
        acc.y += __shfl_xor(acc.y, off, 64);
        acc.z += __shfl_xor(acc.z, off, 64);
        acc.w += __shfl_xor(acc.w, off, 64);
    }
    if (grp == 0) {
        acc.x = fmaxf(acc.x, 0.f);
        acc.y = fmaxf(acc.y, 0.f);
        acc.z = fmaxf(acc.z, 0.f);
        acc.w = fmaxf(acc.w, 0.f);
        agg4[(size_t)c * 16 + f4] = acc;
    }
}

// ---------------------------------------------------------------------------
// Final: out = hin @ W2 + b2;  hin already relu'd. W2[64,40]
// ---------------------------------------------------------------------------
__global__ __launch_bounds__(256) void k_final(const float* __restrict__ hin,
                                               const float* __restrict__ W,
                                               const float* __restrict__ bias,
                                               float* __restrict__ out, int n) {
    __shared__ float xs[64 * 68];
    __shared__ float ws[64 * 40];
    const int tid = threadIdx.x;
    const int row0 = blockIdx.x * 64;

    for (int i = tid; i < 640; i += 256)
        ((float4*)ws)[i] = ((const float4*)W)[i];
#pragma unroll
    for (int i = 0; i < 4; ++i) {
        int f = tid + i * 256;
        int r = f >> 4;
        int c = (f & 15) * 4;
        int row = row0 + r;
        float4 v = make_float4(0.f, 0.f, 0.f, 0.f);
        if (row < n) v = *(const float4*)(hin + (size_t)row * 64 + c);
        *(float4*)(xs + r * 68 + c) = v;
    }
    __syncthreads();

    const int tx = tid & 15, ty = tid >> 4;
    if (tx < 10) {
        float acc[4][4] = {};
#pragma unroll
        for (int kk = 0; kk < 64; kk += 4) {
            float4 a[4], b[4];
#pragma unroll
            for (int j = 0; j < 4; ++j)
                a[j] = *(const float4*)(xs + (ty * 4 + j) * 68 + kk);
#pragma unroll
            for (int q = 0; q < 4; ++q)
                b[q] = *(const float4*)(ws + (kk + q) * 40 + tx * 4);
#pragma unroll
            for (int j = 0; j < 4; ++j) {
                float aj[4] = {a[j].x, a[j].y, a[j].z, a[j].w};
#pragma unroll
                for (int q = 0; q < 4; ++q) {
                    acc[j][0] = fmaf(aj[q], b[q].x, acc[j][0]);
                    acc[j][1] = fmaf(aj[q], b[q].y, acc[j][1]);
                    acc[j][2] = fmaf(aj[q], b[q].z, acc[j][2]);
                    acc[j][3] = fmaf(aj[q], b[q].w, acc[j][3]);
                }
            }
        }
        float4 bb = *(const float4*)(bias + tx * 4);
#pragma unroll
        for (int j = 0; j < 4; ++j) {
            int row = row0 + ty * 4 + j;
            if (row < n) {
                float4 o = make_float4(acc[j][0] + bb.x, acc[j][1] + bb.y,
                                       acc[j][2] + bb.z, acc[j][3] + bb.w);
                *(float4*)(out + (size_t)row * 40 + tx * 4) = o;
            }
        }
    }
}

extern "C" void kernel_launch(void* const* d_in, const int* in_sizes, int n_in,
                              void* d_out, int out_size, void* d_ws, size_t ws_size,
                              hipStream_t stream) {
    const float* x   = (const float*)d_in[0];
    const int*   ei  = (const int*)d_in[1];
    const float* ew  = (const float*)d_in[2];
    const float* W1  = (const float*)d_in[3];
    const float* b1  = (const float*)d_in[4];
    const float* Wc1 = (const float*)d_in[5];
    const float* bc1 = (const float*)d_in[6];
    const float* Wc2 = (const float*)d_in[7];
    const float* bc2 = (const float*)d_in[8];
    const float* W2  = (const float*)d_in[9];
    const float* b2  = (const float*)d_in[10];
    float* out = (float*)d_out;

    const int N = in_sizes[0] / 256;
    const int E = in_sizes[2];
    const int* row = ei;
    const int* col = ei + E;

    // workspace layout (16B-aligned chunks first):
    // recs[E int2] | bufA[64N f] | bufB[64N f] | deg[N f] | cnt[N i] | ptr[N+1 i] | cursor[N i] | bsum[512 i]
    int2*  recs   = (int2*)d_ws;
    float* bufA   = (float*)(recs + E);
    float* bufB   = bufA + (size_t)N * 64;
    float* deg    = bufB + (size_t)N * 64;
    int*   cnt    = (int*)(deg + N);
    int*   ptr    = cnt + N;
    int*   cursor = ptr + N + 1;
    int*   bsum   = cursor + N;

    const int gN = (N + 255) / 256;   // 391
    const int gE = (E + 255) / 256;   // 6250
    const int gG = (N + 63) / 64;     // 1563
    const int gA = (N + 3) / 4;       // 25000

    // --- graph preprocessing (shared by both convs) ---
    k_init<<<gN, 256, 0, stream>>>(deg, cnt, N);
    k_deg_accum<<<gE, 256, 0, stream>>>(col, ew, deg, cnt, E);
    k_dinv<<<gN, 256, 0, stream>>>(deg, N);
    k_scan1<<<gN, 256, 0, stream>>>(cnt, ptr, bsum, N);
    k_scan2<<<1, 512, 0, stream>>>(bsum, gN);
    k_scan3<<<gN, 256, 0, stream>>>(ptr, bsum, cursor, N, E);
    k_scatter<<<gE, 256, 0, stream>>>(row, col, ew, deg, cursor, recs, E);

    // --- layer 1: h1 = relu(x@W1+b1) -> bufA ---
    k_gemm1<<<gG, 256, 0, stream>>>(x, W1, b1, bufA, N);

    // --- conv1: t1 = h1@Wc1 -> bufB; agg1 = relu(csr_agg) -> bufA ---
    k_conv<<<gG, 256, 0, stream>>>(bufA, Wc1, bufB, N);
    k_agg<<<gA, 256, 0, stream>>>(ptr, recs, deg, bc1, (const float4*)bufB,
                                  (float4*)bufA, N);

    // --- conv2: t2 = agg1@Wc2 -> bufB; agg2 = relu(csr_agg) -> bufA ---
    k_conv<<<gG, 256, 0, stream>>>(bufA, Wc2, bufB, N);
    k_agg<<<gA, 256, 0, stream>>>(ptr, recs, deg, bc2, (const float4*)bufB,
                                  (float4*)bufA, N);

    // --- out = agg2 @ W2 + b2 ---
    k_final<<<gG, 256, 0, stream>>>(bufA, W2, b2, out, N);
}

// Round 3
// 588.184 us; speedup vs baseline: 1.8582x; 1.1841x over previous
//
#include <hip/hip_runtime.h>

// ---------------------------------------------------------------------------
// GCN forward:  relu(x@W1+b1) -> gcnconv(Wc1) -> relu -> gcnconv(Wc2) -> relu
//               -> @W2 + b2
//
// R3: CSR build with ONE random atomic per edge. k_hist keeps the rank
// returned by the cnt atomic; scatter is atomic-free (ptr+rank); deg is
// computed from the CSR (no atomics); norm applied on the fly in k_agg.
// ---------------------------------------------------------------------------

__global__ __launch_bounds__(256) void k_zero_cnt(int* __restrict__ cnt, int n) {
    int i = blockIdx.x * 256 + threadIdx.x;
    if (i < n) cnt[i] = 0;
}

// rank[e] = position of edge e within its destination bucket
__global__ __launch_bounds__(256) void k_hist(const int* __restrict__ col,
                                              int* __restrict__ cnt,
                                              int* __restrict__ rank, int ne) {
    int i = blockIdx.x * 256 + threadIdx.x;
    if (i < ne) rank[i] = atomicAdd(&cnt[col[i]], 1);
}

// --- two-level exclusive scan of cnt[n] -> ptr ----------------------------
__global__ __launch_bounds__(256) void k_scan1(const int* __restrict__ cnt,
                                               int* __restrict__ ptr,
                                               int* __restrict__ bsum, int n) {
    __shared__ int s[256];
    const int t = threadIdx.x;
    const int i = blockIdx.x * 256 + t;
    int v = (i < n) ? cnt[i] : 0;
    s[t] = v;
    __syncthreads();
#pragma unroll
    for (int off = 1; off < 256; off <<= 1) {
        int x = (t >= off) ? s[t - off] : 0;
        __syncthreads();
        s[t] += x;
        __syncthreads();
    }
    if (i < n) ptr[i] = s[t] - v;            // local exclusive
    if (t == 255) bsum[blockIdx.x] = s[255]; // block total
}

__global__ __launch_bounds__(512) void k_scan2(int* __restrict__ bsum, int nb) {
    __shared__ int s[512];
    const int t = threadIdx.x;
    int v = (t < nb) ? bsum[t] : 0;
    s[t] = v;
    __syncthreads();
#pragma unroll
    for (int off = 1; off < 512; off <<= 1) {
        int x = (t >= off) ? s[t - off] : 0;
        __syncthreads();
        s[t] += x;
        __syncthreads();
    }
    if (t < nb) bsum[t] = s[t] - v;          // exclusive block offsets
}

__global__ __launch_bounds__(256) void k_scan3(int* __restrict__ ptr,
                                               const int* __restrict__ bsum,
                                               int n, int etot) {
    int i = blockIdx.x * 256 + threadIdx.x;
    if (i < n) ptr[i] = ptr[i] + bsum[i >> 8];
    if (i == 0) ptr[n] = etot;
}

// --- scatter edges into CSR order (atomic-free) ---------------------------
__global__ __launch_bounds__(256) void k_scatter(const int* __restrict__ row,
                                                 const int* __restrict__ col,
                                                 const float* __restrict__ ew,
                                                 const int* __restrict__ ptr,
                                                 const int* __restrict__ rank,
                                                 int2* __restrict__ recs, int ne) {
    int i = blockIdx.x * 256 + threadIdx.x;
    if (i < ne) {
        int c = col[i];
        int pos = ptr[c] + rank[i];
        recs[pos] = make_int2(row[i], __float_as_int(ew[i]));
    }
}

// --- deg/dinv from CSR: deg[c] = 1 + sum(ew over bucket) ------------------
__global__ __launch_bounds__(256) void k_csr_deg(const int* __restrict__ ptr,
                                                 const int2* __restrict__ recs,
                                                 float* __restrict__ dinv, int n) {
    int i = blockIdx.x * 256 + threadIdx.x;
    if (i < n) {
        int s = ptr[i], e = ptr[i + 1];
        float d = 1.0f;  // self-loop
        for (int j = s; j < e; ++j) d += __int_as_float(recs[j].y);
        dinv[i] = rsqrtf(d);
    }
}

// ---------------------------------------------------------------------------
// GEMM1: h = relu(x @ W1 + b1);  x[N,256], W1[256,64]. 64x64 tile, 4x4 micro.
// ---------------------------------------------------------------------------
__global__ __launch_bounds__(256) void k_gemm1(const float* __restrict__ x,
                                               const float* __restrict__ W,
                                               const float* __restrict__ bias,
                                               float* __restrict__ h, int n) {
    __shared__ float xs[64 * 68];
    __shared__ float ws[64 * 64];
    const int tid = threadIdx.x;
    const int row0 = blockIdx.x * 64;
    const int tx = tid & 15, ty = tid >> 4;
    float acc[4][4] = {};

    for (int kb = 0; kb < 256; kb += 64) {
        __syncthreads();
        {
            const float4* src = (const float4*)(W + kb * 64);
            float4* dst = (float4*)ws;
#pragma unroll
            for (int i = 0; i < 4; ++i) dst[tid + i * 256] = src[tid + i * 256];
        }
#pragma unroll
        for (int i = 0; i < 4; ++i) {
            int f = tid + i * 256;
            int r = f >> 4;
            int c = (f & 15) * 4;
            int row = row0 + r;
            float4 v = make_float4(0.f, 0.f, 0.f, 0.f);
            if (row < n) v = *(const float4*)(x + (size_t)row * 256 + kb + c);
            *(float4*)(xs + r * 68 + c) = v;
        }
        __syncthreads();
#pragma unroll
        for (int kk = 0; kk < 64; kk += 4) {
            float4 a[4], b[4];
#pragma unroll
            for (int j = 0; j < 4; ++j)
                a[j] = *(const float4*)(xs + (ty * 4 + j) * 68 + kk);
#pragma unroll
            for (int q = 0; q < 4; ++q)
                b[q] = *(const float4*)(ws + (kk + q) * 64 + tx * 4);
#pragma unroll
            for (int j = 0; j < 4; ++j) {
                float aj[4] = {a[j].x, a[j].y, a[j].z, a[j].w};
#pragma unroll
                for (int q = 0; q < 4; ++q) {
                    acc[j][0] = fmaf(aj[q], b[q].x, acc[j][0]);
                    acc[j][1] = fmaf(aj[q], b[q].y, acc[j][1]);
                    acc[j][2] = fmaf(aj[q], b[q].z, acc[j][2]);
                    acc[j][3] = fmaf(aj[q], b[q].w, acc[j][3]);
                }
            }
        }
    }
    float4 bb = *(const float4*)(bias + tx * 4);
#pragma unroll
    for (int j = 0; j < 4; ++j) {
        int row = row0 + ty * 4 + j;
        if (row < n) {
            float4 o;
            o.x = fmaxf(acc[j][0] + bb.x, 0.f);
            o.y = fmaxf(acc[j][1] + bb.y, 0.f);
            o.z = fmaxf(acc[j][2] + bb.z, 0.f);
            o.w = fmaxf(acc[j][3] + bb.w, 0.f);
            *(float4*)(h + (size_t)row * 64 + tx * 4) = o;
        }
    }
}

// ---------------------------------------------------------------------------
// Conv dense part: t = hin @ W (pure 64x64 GEMM; bias/self-loop live in k_agg)
// ---------------------------------------------------------------------------
__global__ __launch_bounds__(256) void k_conv(const float* __restrict__ hin,
                                              const float* __restrict__ W,
                                              float* __restrict__ t, int n) {
    __shared__ float xs[64 * 68];
    __shared__ float ws[64 * 64];
    const int tid = threadIdx.x;
    const int row0 = blockIdx.x * 64;
    const int tx = tid & 15, ty = tid >> 4;

    {
        const float4* src = (const float4*)W;
        float4* dst = (float4*)ws;
#pragma unroll
        for (int i = 0; i < 4; ++i) dst[tid + i * 256] = src[tid + i * 256];
    }
#pragma unroll
    for (int i = 0; i < 4; ++i) {
        int f = tid + i * 256;
        int r = f >> 4;
        int c = (f & 15) * 4;
        int row = row0 + r;
        float4 v = make_float4(0.f, 0.f, 0.f, 0.f);
        if (row < n) v = *(const float4*)(hin + (size_t)row * 64 + c);
        *(float4*)(xs + r * 68 + c) = v;
    }
    __syncthreads();

    float acc[4][4] = {};
#pragma unroll
    for (int kk = 0; kk < 64; kk += 4) {
        float4 a[4], b[4];
#pragma unroll
        for (int j = 0; j < 4; ++j)
            a[j] = *(const float4*)(xs + (ty * 4 + j) * 68 + kk);
#pragma unroll
        for (int q = 0; q < 4; ++q)
            b[q] = *(const float4*)(ws + (kk + q) * 64 + tx * 4);
#pragma unroll
        for (int j = 0; j < 4; ++j) {
            float aj[4] = {a[j].x, a[j].y, a[j].z, a[j].w};
#pragma unroll
            for (int q = 0; q < 4; ++q) {
                acc[j][0] = fmaf(aj[q], b[q].x, acc[j][0]);
                acc[j][1] = fmaf(aj[q], b[q].y, acc[j][1]);
                acc[j][2] = fmaf(aj[q], b[q].z, acc[j][2]);
                acc[j][3] = fmaf(aj[q], b[q].w, acc[j][3]);
            }
        }
    }
#pragma unroll
    for (int j = 0; j < 4; ++j) {
        int row = row0 + ty * 4 + j;
        if (row < n)
            *(float4*)(t + (size_t)row * 64 + tx * 4) =
                make_float4(acc[j][0], acc[j][1], acc[j][2], acc[j][3]);
    }
}

// ---------------------------------------------------------------------------
// CSR aggregation: one wave per node c.
//   agg[c] = relu( b + dinv[c]^2 * t[c] + sum_e ew_e*dinv[row_e]*dinv[c] * t[row_e] )
// Lane layout: grp = lane>>4 (edge slot 0..3), f4 = lane&15 (float4 of feature).
// ---------------------------------------------------------------------------
__global__ __launch_bounds__(256) void k_agg(const int* __restrict__ ptr,
                                             const int2* __restrict__ recs,
                                             const float* __restrict__ dinv,
                                             const float* __restrict__ bias,
                                             const float4* __restrict__ t4,
                                             float4* __restrict__ agg4, int n) {
    const int lane = threadIdx.x & 63;
    const int c = blockIdx.x * 4 + (threadIdx.x >> 6);
    if (c >= n) return;
    const int grp = lane >> 4;
    const int f4 = lane & 15;
    const float wc = dinv[c];

    float4 acc = make_float4(0.f, 0.f, 0.f, 0.f);
    if (grp == 0) {
        float s = wc * wc;
        float4 tv = t4[(size_t)c * 16 + f4];
        float4 bb = ((const float4*)bias)[f4];
        acc.x = fmaf(s, tv.x, bb.x);
        acc.y = fmaf(s, tv.y, bb.y);
        acc.z = fmaf(s, tv.z, bb.z);
        acc.w = fmaf(s, tv.w, bb.w);
    }

    const int eEnd = ptr[c + 1];
    int e = ptr[c] + grp;
    int2 rec = (e < eEnd) ? recs[e] : make_int2(0, 0);
    while (e < eEnd) {
        int2 cur = rec;
        e += 4;
        if (e < eEnd) rec = recs[e];
        float w = __int_as_float(cur.y) * wc * dinv[cur.x];
        float4 tv = t4[(size_t)cur.x * 16 + f4];
        acc.x = fmaf(w, tv.x, acc.x);
        acc.y = fmaf(w, tv.y, acc.y);
        acc.z = fmaf(w, tv.z, acc.z);
        acc.w = fmaf(w, tv.w, acc.w);
    }

    // reduce across the 4 groups (lanes differing in bits 4,5)
#pragma unroll
    for (int off = 16; off < 64; off <<= 1) {
        acc.x += __shfl_xor(acc.x, off, 64);
        acc.y += __shfl_xor(acc.y, off, 64);
        acc.z += __shfl_xor(acc.z, off, 64);
        acc.w += __shfl_xor(acc.w, off, 64);
    }
    if (grp == 0) {
        acc.x = fmaxf(acc.x, 0.f);
        acc.y = fmaxf(acc.y, 0.f);
        acc.z = fmaxf(acc.z, 0.f);
        acc.w = fmaxf(acc.w, 0.f);
        agg4[(size_t)c * 16 + f4] = acc;
    }
}

// ---------------------------------------------------------------------------
// Final: out = hin @ W2 + b2;  hin already relu'd. W2[64,40]
// ---------------------------------------------------------------------------
__global__ __launch_bounds__(256) void k_final(const float* __restrict__ hin,
                                               const float* __restrict__ W,
                                               const float* __restrict__ bias,
                                               float* __restrict__ out, int n) {
    __shared__ float xs[64 * 68];
    __shared__ float ws[64 * 40];
    const int tid = threadIdx.x;
    const int row0 = blockIdx.x * 64;

    for (int i = tid; i < 640; i += 256)
        ((float4*)ws)[i] = ((const float4*)W)[i];
#pragma unroll
    for (int i = 0; i < 4; ++i) {
        int f = tid + i * 256;
        int r = f >> 4;
        int c = (f & 15) * 4;
        int row = row0 + r;
        float4 v = make_float4(0.f, 0.f, 0.f, 0.f);
        if (row < n) v = *(const float4*)(hin + (size_t)row * 64 + c);
        *(float4*)(xs + r * 68 + c) = v;
    }
    __syncthreads();

    const int tx = tid & 15, ty = tid >> 4;
    if (tx < 10) {
        float acc[4][4] = {};
#pragma unroll
        for (int kk = 0; kk < 64; kk += 4) {
            float4 a[4], b[4];
#pragma unroll
            for (int j = 0; j < 4; ++j)
                a[j] = *(const float4*)(xs + (ty * 4 + j) * 68 + kk);
#pragma unroll
            for (int q = 0; q < 4; ++q)
                b[q] = *(const float4*)(ws + (kk + q) * 40 + tx * 4);
#pragma unroll
            for (int j = 0; j < 4; ++j) {
                float aj[4] = {a[j].x, a[j].y, a[j].z, a[j].w};
#pragma unroll
                for (int q = 0; q < 4; ++q) {
                    acc[j][0] = fmaf(aj[q], b[q].x, acc[j][0]);
                    acc[j][1] = fmaf(aj[q], b[q].y, acc[j][1]);
                    acc[j][2] = fmaf(aj[q], b[q].z, acc[j][2]);
                    acc[j][3] = fmaf(aj[q], b[q].w, acc[j][3]);
                }
            }
        }
        float4 bb = *(const float4*)(bias + tx * 4);
#pragma unroll
        for (int j = 0; j < 4; ++j) {
            int row = row0 + ty * 4 + j;
            if (row < n) {
                float4 o = make_float4(acc[j][0] + bb.x, acc[j][1] + bb.y,
                                       acc[j][2] + bb.z, acc[j][3] + bb.w);
                *(float4*)(out + (size_t)row * 40 + tx * 4) = o;
            }
        }
    }
}

extern "C" void kernel_launch(void* const* d_in, const int* in_sizes, int n_in,
                              void* d_out, int out_size, void* d_ws, size_t ws_size,
                              hipStream_t stream) {
    const float* x   = (const float*)d_in[0];
    const int*   ei  = (const int*)d_in[1];
    const float* ew  = (const float*)d_in[2];
    const float* W1  = (const float*)d_in[3];
    const float* b1  = (const float*)d_in[4];
    const float* Wc1 = (const float*)d_in[5];
    const float* bc1 = (const float*)d_in[6];
    const float* Wc2 = (const float*)d_in[7];
    const float* bc2 = (const float*)d_in[8];
    const float* W2  = (const float*)d_in[9];
    const float* b2  = (const float*)d_in[10];
    float* out = (float*)d_out;

    const int N = in_sizes[0] / 256;
    const int E = in_sizes[2];
    const int* row = ei;
    const int* col = ei + E;

    // workspace layout (floats/ints; 16B-aligned chunks first):
    // recs[E int2] | bufA[64N f] | bufB[64N f] | dinv[N f] | cnt[N i] | ptr[N+1 i] | bsum[512 i]
    // rank[E] aliases the head of bufA: scatter finishes before gemm1 writes h1.
    int2*  recs = (int2*)d_ws;
    float* bufA = (float*)(recs + E);
    float* bufB = bufA + (size_t)N * 64;
    float* dinv = bufB + (size_t)N * 64;
    int*   cnt  = (int*)(dinv + N);
    int*   ptr  = cnt + N;
    int*   bsum = ptr + N + 1;
    int*   rank = (int*)bufA;   // E ints <= 64N floats; dead once k_scatter completes

    const int gN = (N + 255) / 256;   // 391
    const int gE = (E + 255) / 256;   // 6250
    const int gG = (N + 63) / 64;     // 1563
    const int gA = (N + 3) / 4;       // 25000

    // --- CSR build (shared by both convs); ONE random atomic per edge ---
    k_zero_cnt<<<gN, 256, 0, stream>>>(cnt, N);
    k_hist<<<gE, 256, 0, stream>>>(col, cnt, rank, E);
    k_scan1<<<gN, 256, 0, stream>>>(cnt, ptr, bsum, N);
    k_scan2<<<1, 512, 0, stream>>>(bsum, gN);
    k_scan3<<<gN, 256, 0, stream>>>(ptr, bsum, N, E);
    k_scatter<<<gE, 256, 0, stream>>>(row, col, ew, ptr, rank, recs, E);
    k_csr_deg<<<gN, 256, 0, stream>>>(ptr, recs, dinv, N);

    // --- layer 1: h1 = relu(x@W1+b1) -> bufA (rank now dead) ---
    k_gemm1<<<gG, 256, 0, stream>>>(x, W1, b1, bufA, N);

    // --- conv1: t1 = h1@Wc1 -> bufB; agg1 = relu(csr_agg) -> bufA ---
    k_conv<<<gG, 256, 0, stream>>>(bufA, Wc1, bufB, N);
    k_agg<<<gA, 256, 0, stream>>>(ptr, recs, dinv, bc1, (const float4*)bufB,
                                  (float4*)bufA, N);

    // --- conv2: t2 = agg1@Wc2 -> bufB; agg2 = relu(csr_agg) -> bufA ---
    k_conv<<<gG, 256, 0, stream>>>(bufA, Wc2, bufB, N);
    k_agg<<<gA, 256, 0, stream>>>(ptr, recs, dinv, bc2, (const float4*)bufB,
                                  (float4*)bufA, N);

    // --- out = agg2 @ W2 + b2 ---
    k_final<<<gG, 256, 0, stream>>>(bufA, W2, b2, out, N);
}